// Round 2
// baseline (603.677 us; speedup 1.0000x reference)
//
#include <hip/hip_runtime.h>

typedef _Float16 half8_t __attribute__((ext_vector_type(8)));
typedef _Float16 half4_t __attribute__((ext_vector_type(4)));

#define NU 100000
#define NI 50000
#define NR (NU + NI)          // unified rows: users then items
#define D 64
#define SEG 10                // source segments of 16384 rows = 2 MB fp16 (per-XCD L2 resident)
#define SEGSH 14              // seg = src >> 14
#define CHK 147               // dest-row chunks of 1024 rows (147*1024 >= NR)
#define COARSE (SEG * CHK)    // 1470 coarse buckets, key = seg*CHK + (dest>>10)
#define CAP 8800              // csr LDS staging capacity (bucket mean ~4350, max ~6400)
#define CHUNK 6144            // placements per block in count/place
#define RPT 6                 // records per thread (CHUNK / 1024)
#define NT4 (NR * 16)         // float4 count of full table

// out = concat(ue, ie) fp32; curh = same data fp16
__global__ void init_kernel(const float4* __restrict__ ue, const float4* __restrict__ ie,
                            float4* __restrict__ out, half4_t* __restrict__ curh) {
    int idx = blockIdx.x * 256 + threadIdx.x;
    if (idx >= NT4) return;
    float4 v = (idx < NU * 16) ? ue[idx] : ie[idx - NU * 16];
    out[idx] = v;
    half4_t h;
    h[0] = (_Float16)v.x; h[1] = (_Float16)v.y; h[2] = (_Float16)v.z; h[3] = (_Float16)v.w;
    curh[idx] = h;
}

// placement p -> (dest,src) in unified row space (items offset by NU)
__device__ __forceinline__ void place_ds(int p, const int* ui_r, const int* ui_c,
                                         const int* uu_r, const int* uu_c,
                                         const int* ii_r, const int* ii_c,
                                         int n_ui, int n_uu, int& dest, int& src) {
    if (p < 2 * n_ui) {
        int e = p >> 1;
        int r = ui_r[e], c = ui_c[e];
        if (p & 1) { dest = NU + c; src = r; }
        else       { dest = r;      src = NU + c; }
    } else if (p < 2 * n_ui + n_uu) {
        int e = p - 2 * n_ui;
        dest = uu_r[e]; src = uu_c[e];
    } else {
        int e = p - 2 * n_ui - n_uu;
        dest = NU + ii_r[e]; src = NU + ii_c[e];
    }
}

// per-block coarse histogram over (seg, dest-chunk) -> m[block][COARSE]
__global__ void count_kernel(const int* __restrict__ ui_r, const int* __restrict__ ui_c,
                             const int* __restrict__ uu_r, const int* __restrict__ uu_c,
                             const int* __restrict__ ii_r, const int* __restrict__ ii_c,
                             int* __restrict__ m, int n_ui, int n_uu, int nnzt) {
    __shared__ int cnt[COARSE];
    int tid = threadIdx.x;
    for (int i = tid; i < COARSE; i += 1024) cnt[i] = 0;
    __syncthreads();
    int blk0 = blockIdx.x * CHUNK;
#pragma unroll
    for (int k = 0; k < RPT; k++) {
        int p = blk0 + k * 1024 + tid;
        if (p < nnzt) {
            int dest, src;
            place_ds(p, ui_r, ui_c, uu_r, uu_c, ii_r, ii_c, n_ui, n_uu, dest, src);
            int key = (src >> SEGSH) * CHK + (dest >> 10);
            atomicAdd(&cnt[key], 1);
        }
    }
    __syncthreads();
    for (int i = tid; i < COARSE; i += 1024) m[blockIdx.x * COARSE + i] = cnt[i];
}

// one block per coarse bucket: parallel column sum of m -> tots[c]
__global__ void colsum_kernel(const int* __restrict__ m, int* __restrict__ tots, int nblk) {
    __shared__ int s[256];
    int c = blockIdx.x, tid = threadIdx.x;
    int sum = 0;
    for (int b = tid; b < nblk; b += 256) sum += m[b * COARSE + c];
    s[tid] = sum;
    __syncthreads();
    for (int off = 128; off > 0; off >>= 1) {
        if (tid < off) s[tid] += s[tid + off];
        __syncthreads();
    }
    if (tid == 0) tots[c] = s[0];
}

// single block: exclusive scan of tots (len COARSE<=2048) -> coarse_base
__global__ void scan1_kernel(const int* __restrict__ tots, int* __restrict__ coarse_base) {
    __shared__ int s[2048];
    int tid = threadIdx.x;
    int x0 = (tid < COARSE) ? tots[tid] : 0;
    int x1 = (tid + 1024 < COARSE) ? tots[tid + 1024] : 0;
    s[tid] = x0; s[tid + 1024] = x1;
    __syncthreads();
    for (int off = 1; off < 2048; off <<= 1) {
        int a = (tid >= off) ? s[tid - off] : 0;
        int b = (tid + 1024 >= off) ? s[tid + 1024 - off] : 0;
        __syncthreads();
        s[tid] += a; s[tid + 1024] += b;
        __syncthreads();
    }
    if (tid < COARSE) coarse_base[tid] = s[tid] - x0;
    if (tid + 1024 < COARSE) coarse_base[tid + 1024] = s[tid + 1024] - x1;
    if (tid == 0) coarse_base[COARSE] = s[2047];
}

// one block per coarse bucket: segmented exclusive scan down the column,
// rewriting m in place as absolute per-(block,bucket) base offsets.
__global__ void rebase_kernel(int* __restrict__ m, const int* __restrict__ coarse_base, int nblk) {
    __shared__ int s[256];
    int c = blockIdx.x, tid = threadIdx.x;
    int K = (nblk + 255) / 256;
    int b0 = tid * K;
    int b1 = b0 + K;
    if (b1 > nblk) b1 = nblk;
    int sum = 0;
    for (int b = b0; b < b1; b++) sum += m[b * COARSE + c];
    s[tid] = sum;
    __syncthreads();
    for (int off = 1; off < 256; off <<= 1) {
        int t = (tid >= off) ? s[tid - off] : 0;
        __syncthreads();
        s[tid] += t;
        __syncthreads();
    }
    int run = coarse_base[c] + s[tid] - sum;   // exclusive prefix for this thread's range
    for (int b = b0; b < b1; b++) {
        int v = m[b * COARSE + c];
        m[b * COARSE + c] = run;
        run += v;
    }
}

// LDS-staged bucket sort per block -> fully coalesced scratch writeout.
// record: x = dl<<18 | src (dl = dest & 1023) ; y = (key<<16) | val_fp16
__global__ void place_kernel(const int* __restrict__ ui_r, const int* __restrict__ ui_c,
                             const float* __restrict__ ui_v,
                             const int* __restrict__ uu_r, const int* __restrict__ uu_c,
                             const float* __restrict__ uu_v,
                             const int* __restrict__ ii_r, const int* __restrict__ ii_c,
                             const float* __restrict__ ii_v,
                             const int* __restrict__ m, uint2* __restrict__ scratch,
                             int n_ui, int n_uu, int nnzt) {
    __shared__ uint2 rec[CHUNK];      // 48 KB
    __shared__ int cnt[2048];         // 8 KB (counts, padded for scan)
    __shared__ int lb[2048];          // 8 KB (inclusive scan)
    __shared__ int base_s[COARSE];    // ~5.9 KB
    int tid = threadIdx.x;
    cnt[tid] = 0; cnt[tid + 1024] = 0;
    __syncthreads();
    int blk0 = blockIdx.x * CHUNK;
    int rk[RPT];
#pragma unroll
    for (int k = 0; k < RPT; k++) {
        int p = blk0 + k * 1024 + tid;
        rk[k] = -1;
        if (p < nnzt) {
            int dest, src;
            place_ds(p, ui_r, ui_c, uu_r, uu_c, ii_r, ii_c, n_ui, n_uu, dest, src);
            int key = (src >> SEGSH) * CHK + (dest >> 10);
            int lr = atomicAdd(&cnt[key], 1);   // < 6144 -> 14 bits
            rk[k] = (key << 14) | lr;
        }
    }
    __syncthreads();
    // inclusive scan of cnt (2048 wide) -> lb; excl[c] = lb[c] - cnt[c]
    int o0 = cnt[tid], o1 = cnt[tid + 1024];
    lb[tid] = o0; lb[tid + 1024] = o1;
    __syncthreads();
    for (int off = 1; off < 2048; off <<= 1) {
        int a = (tid >= off) ? lb[tid - off] : 0;
        int b = (tid + 1024 >= off) ? lb[tid + 1024 - off] : 0;
        __syncthreads();
        lb[tid] += a; lb[tid + 1024] += b;
        __syncthreads();
    }
    for (int i = tid; i < COARSE; i += 1024) base_s[i] = m[blockIdx.x * COARSE + i];
    __syncthreads();
    // phase 2: decode records, scatter into LDS grouped by bucket
#pragma unroll
    for (int k = 0; k < RPT; k++) {
        int p = blk0 + k * 1024 + tid;
        if (p >= nnzt) continue;
        int dest, src;
        float v;
        if (p < 2 * n_ui) {
            int e = p >> 1;
            int r = ui_r[e], cc = ui_c[e];
            v = ui_v[e];
            if (p & 1) { dest = NU + cc; src = r; }
            else       { dest = r; src = NU + cc; }
        } else if (p < 2 * n_ui + n_uu) {
            int e = p - 2 * n_ui;
            dest = uu_r[e]; src = uu_c[e]; v = uu_v[e];
        } else {
            int e = p - 2 * n_ui - n_uu;
            dest = NU + ii_r[e]; src = NU + ii_c[e]; v = ii_v[e];
        }
        int c  = rk[k] >> 14;
        int lr = rk[k] & 0x3FFF;
        int dl = dest & 1023;
        _Float16 hv = (_Float16)v;
        unsigned short us;
        __builtin_memcpy(&us, &hv, 2);
        rec[(lb[c] - cnt[c]) + lr] = make_uint2(((unsigned)dl << 18) | (unsigned)src,
                                                ((unsigned)c << 16) | (unsigned)us);
    }
    __syncthreads();
    // phase 3: coalesced streamed writeout
    int ntot = lb[2047];
    for (int i = tid; i < ntot; i += 1024) {
        uint2 r = rec[i];
        int c = r.y >> 16;
        scratch[base_s[c] + (i - (lb[c] - cnt[c]))] = r;
    }
}

// one block per coarse bucket (seg, dest-chunk): fine histogram over row-in-chunk,
// scan, LDS-staged scatter, coalesced writeout. Emits P[seg][row] edge bases.
// pk_src holds ROW BYTE OFFSETS (src*128).
__global__ void csr_kernel(const uint2* __restrict__ scratch, const int* __restrict__ coarse_base,
                           int* __restrict__ P, int* __restrict__ pk_src,
                           unsigned short* __restrict__ pk_val) {
    __shared__ int s[1024];
    __shared__ int fine[1024];
    __shared__ int fill[1024];
    __shared__ int lsrc[CAP];            // 35.2 KB
    __shared__ unsigned short lval[CAP]; // 17.6 KB
    int c = blockIdx.x, tid = threadIdx.x;
    int seg = c / CHK, chunk = c % CHK;
    int rbeg = chunk << 10;
    int rcnt = NR - rbeg;
    if (rcnt > 1024) rcnt = 1024;
    if (rcnt < 0) rcnt = 0;
    int base = coarse_base[c], end = coarse_base[c + 1];
    int n = end - base;
    fine[tid] = 0;
    __syncthreads();
    for (int i = tid; i < n; i += 1024)
        atomicAdd(&fine[scratch[base + i].x >> 18], 1);
    __syncthreads();
    int own = fine[tid];
    s[tid] = own;
    __syncthreads();
    for (int off = 1; off < 1024; off <<= 1) {
        int t = (tid >= off) ? s[tid - off] : 0;
        __syncthreads();
        s[tid] += t;
        __syncthreads();
    }
    int excl = s[tid] - own;
    if (tid < rcnt) P[seg * NR + rbeg + tid] = base + excl;
    if (c == COARSE - 1 && tid == 0) P[SEG * NR] = coarse_base[COARSE];  // sentinel
    fill[tid] = excl;
    __syncthreads();
    if (n <= CAP) {
        for (int i = tid; i < n; i += 1024) {
            uint2 r = scratch[base + i];
            int dl = r.x >> 18;
            int slot = atomicAdd(&fill[dl], 1);
            lsrc[slot] = r.x & 0x3FFFF;
            lval[slot] = (unsigned short)r.y;
        }
        __syncthreads();
        for (int i = tid; i < n; i += 1024) {
            pk_src[base + i] = lsrc[i] << 7;   // byte offset: src * 128
            pk_val[base + i] = lval[i];
        }
    } else {
        for (int i = tid; i < n; i += 1024) {
            uint2 r = scratch[base + i];
            int dl = r.x >> 18;
            int slot = atomicAdd(&fill[dl], 1);
            pk_src[base + slot] = (r.x & 0x3FFFF) << 7;
            pk_val[base + slot] = (unsigned short)r.y;
        }
    }
}

// ---- segment-swept SpMM: 8-lane group owns 4 rows, fp32 acc in regs,
// sweeps 10 source segments in order (soft lockstep across the resident grid)
__device__ __forceinline__ void run_row(int b, int e, const int* __restrict__ pk_src,
                                        const _Float16* __restrict__ pk_val,
                                        const char* __restrict__ sph, float (&acc)[8]) {
    for (int j = b; j < e; j += 4) {
        int j1 = (j + 1 < e) ? j + 1 : b;
        int j2 = (j + 2 < e) ? j + 2 : b;
        int j3 = (j + 3 < e) ? j + 3 : b;
        int s0 = pk_src[j];
        int s1 = pk_src[j1];
        int s2 = pk_src[j2];
        int s3 = pk_src[j3];
        float v0 = (float)pk_val[j];
        float v1 = (j + 1 < e) ? (float)pk_val[j1] : 0.f;
        float v2 = (j + 2 < e) ? (float)pk_val[j2] : 0.f;
        float v3 = (j + 3 < e) ? (float)pk_val[j3] : 0.f;
        half8_t x0 = *(const half8_t*)(sph + s0);
        half8_t x1 = *(const half8_t*)(sph + s1);
        half8_t x2 = *(const half8_t*)(sph + s2);
        half8_t x3 = *(const half8_t*)(sph + s3);
#pragma unroll
        for (int k = 0; k < 8; k++)
            acc[k] += v0 * (float)x0[k] + v1 * (float)x1[k]
                    + v2 * (float)x2[k] + v3 * (float)x3[k];
    }
}

__device__ __forceinline__ void epi_row(int row, int fl, float (&a)[8],
                                        half8_t* __restrict__ nexth, float4* __restrict__ out,
                                        float final_scale, int store_next) {
    float h[8];
#pragma unroll
    for (int k = 0; k < 8; k++) h[k] = 0.5f * a[k];
    if (store_next) {
        half8_t hh;
#pragma unroll
        for (int k = 0; k < 8; k++) hh[k] = (_Float16)h[k];
        nexth[row * 8 + fl] = hh;
    }
    float4* op = out + (size_t)row * 16 + fl * 2;
    float4 o0 = op[0];
    float4 o1 = op[1];
    o0.x = (o0.x + h[0]) * final_scale;
    o0.y = (o0.y + h[1]) * final_scale;
    o0.z = (o0.z + h[2]) * final_scale;
    o0.w = (o0.w + h[3]) * final_scale;
    o1.x = (o1.x + h[4]) * final_scale;
    o1.y = (o1.y + h[5]) * final_scale;
    o1.z = (o1.z + h[6]) * final_scale;
    o1.w = (o1.w + h[7]) * final_scale;
    op[0] = o0;
    op[1] = o1;
}

__global__ void spmm_seg(const int* __restrict__ P, const int* __restrict__ pk_src,
                         const _Float16* __restrict__ pk_val, const half8_t* __restrict__ src,
                         half8_t* __restrict__ nexth, float4* __restrict__ out,
                         float final_scale, int store_next) {
    int gid = (int)((blockIdx.x * blockDim.x + threadIdx.x) >> 3);
    int fl  = threadIdx.x & 7;
    int r0  = gid << 2;
    if (r0 >= NR) return;
    const char* sph = (const char*)src + (fl << 4);

    float a0[8], a1[8], a2[8], a3[8];
#pragma unroll
    for (int k = 0; k < 8; k++) { a0[k] = 0.f; a1[k] = 0.f; a2[k] = 0.f; a3[k] = 0.f; }

    for (int sgi = 0; sgi < SEG; sgi++) {
        const int* Ps = P + sgi * NR + r0;           // NR%4==0, r0%4==0 -> 16B aligned
        int4 bb = *(const int4*)Ps;
        int e3 = Ps[4];
        run_row(bb.x, bb.y, pk_src, pk_val, sph, a0);
        run_row(bb.y, bb.z, pk_src, pk_val, sph, a1);
        run_row(bb.z, bb.w, pk_src, pk_val, sph, a2);
        run_row(bb.w, e3,   pk_src, pk_val, sph, a3);
    }

    epi_row(r0 + 0, fl, a0, nexth, out, final_scale, store_next);
    epi_row(r0 + 1, fl, a1, nexth, out, final_scale, store_next);
    epi_row(r0 + 2, fl, a2, nexth, out, final_scale, store_next);
    epi_row(r0 + 3, fl, a3, nexth, out, final_scale, store_next);
}

extern "C" void kernel_launch(void* const* d_in, const int* in_sizes, int n_in,
                              void* d_out, int out_size, void* d_ws, size_t ws_size,
                              hipStream_t stream) {
    const float* ue      = (const float*)d_in[0];
    const float* ie      = (const float*)d_in[1];
    const float* uu_val  = (const float*)d_in[2];
    const float* ui_val  = (const float*)d_in[3];
    const float* ii_val  = (const float*)d_in[4];
    const int*   uu_rows = (const int*)d_in[5];
    const int*   uu_cols = (const int*)d_in[6];
    const int*   ui_rows = (const int*)d_in[7];
    const int*   ui_cols = (const int*)d_in[8];
    const int*   ii_rows = (const int*)d_in[9];
    const int*   ii_cols = (const int*)d_in[10];

    const int NNZ_UU = in_sizes[2];
    const int NNZ_UI = in_sizes[3];
    const int NNZ_II = in_sizes[4];
    const int NNZT   = 2 * NNZ_UI + NNZ_UU + NNZ_II;
    const int NBLK   = (NNZT + CHUNK - 1) / CHUNK;

    float* out = (float*)d_out;

    // ---- workspace layout (~115 MB) ----
    char* wsb = (char*)d_ws;
    half8_t* curh   = (half8_t*)wsb;                         // NR*128 B = 19.2 MB
    uint2*   scratch = (uint2*)(wsb + (size_t)NR * 128);     // NNZT*8 = 51.2 MB
    half8_t* nexth  = (half8_t*)scratch;                     // aliases scratch (dead after csr)
    int*     pk_src = (int*)(scratch + NNZT);                // NNZT*4
    unsigned short* pk_val = (unsigned short*)(pk_src + NNZT); // NNZT*2
    size_t moff = (size_t)NR * 128 + (size_t)NNZT * 14;
    moff = (moff + 15) & ~(size_t)15;
    int*     m = (int*)(wsb + moff);                         // NBLK*COARSE (~6.1 MB)
    int*     P = m;                                          // aliases m (m dead after place)
    size_t m_ints = (size_t)NBLK * COARSE;
    size_t p_ints = (size_t)SEG * NR + 16;
    if (m_ints < p_ints) m_ints = p_ints;
    int*     coarse_base = m + m_ints;                       // COARSE+1
    int*     tots   = coarse_base + (COARSE + 1);            // COARSE

    init_kernel<<<(NT4 + 255) / 256, 256, 0, stream>>>(
        (const float4*)ue, (const float4*)ie, (float4*)out, (half4_t*)curh);

    count_kernel<<<NBLK, 1024, 0, stream>>>(
        ui_rows, ui_cols, uu_rows, uu_cols, ii_rows, ii_cols, m, NNZ_UI, NNZ_UU, NNZT);

    colsum_kernel<<<COARSE, 256, 0, stream>>>(m, tots, NBLK);
    scan1_kernel<<<1, 1024, 0, stream>>>(tots, coarse_base);
    rebase_kernel<<<COARSE, 256, 0, stream>>>(m, coarse_base, NBLK);

    place_kernel<<<NBLK, 1024, 0, stream>>>(
        ui_rows, ui_cols, ui_val, uu_rows, uu_cols, uu_val,
        ii_rows, ii_cols, ii_val, m, scratch, NNZ_UI, NNZ_UU, NNZT);

    csr_kernel<<<COARSE, 1024, 0, stream>>>(scratch, coarse_base, P, pk_src, pk_val);

    int groups = (NR + 3) / 4;                    // 4 rows per 8-lane group
    int sblocks = (groups + 31) / 32;             // 32 groups per 256-thread block -> 1172 blocks

    // layer 1: gather curh -> nexth, out += h
    spmm_seg<<<sblocks, 256, 0, stream>>>(
        P, pk_src, (const _Float16*)pk_val, curh, nexth, (float4*)out, 1.0f, 1);

    // layer 2: gather nexth, out = (out + h) / 3
    spmm_seg<<<sblocks, 256, 0, stream>>>(
        P, pk_src, (const _Float16*)pk_val, nexth, curh, (float4*)out, 1.0f / 3.0f, 0);
}